// Round 1
// baseline (385.208 us; speedup 1.0000x reference)
//
#include <hip/hip_runtime.h>
#include <hip/hip_bf16.h>

#define NTOK 2048      // B*T
#define DMODEL 1024
#define NEXP 8
#define FFN 4096
#define MT 32          // max m-tiles per expert (2048/64)
#define BM 64
#define BN 64
#define BK 64
#define LDSTR 88       // padded LDS stride (bf16 elems); 88*2=176B, 16B-aligned rows

typedef __bf16 bf16x8 __attribute__((ext_vector_type(8)));
typedef __bf16 bf16x4 __attribute__((ext_vector_type(4)));
typedef float f32x4 __attribute__((ext_vector_type(4)));

// ---------------- router ----------------
__global__ __launch_bounds__(256) void router_kernel(
    const float* __restrict__ x, const int* __restrict__ mask,
    const float* __restrict__ rw, int* __restrict__ counts,
    int* __restrict__ tlist, float* __restrict__ gate)
{
  int wid  = threadIdx.x >> 6;
  int lane = threadIdx.x & 63;
  int t = blockIdx.x * 4 + wid;
  if (t >= NTOK) return;

  float acc[NEXP];
#pragma unroll
  for (int e = 0; e < NEXP; e++) acc[e] = 0.f;

  const float* xr = x + (size_t)t * DMODEL;
  for (int i = 0; i < DMODEL / 64; i++) {
    int d = lane + i * 64;
    float xv = xr[d];
#pragma unroll
    for (int e = 0; e < NEXP; e++) acc[e] += xv * rw[e * DMODEL + d];
  }
#pragma unroll
  for (int e = 0; e < NEXP; e++) {
#pragma unroll
    for (int s = 1; s < 64; s <<= 1) acc[e] += __shfl_xor(acc[e], s, 64);
  }

  if (lane == 0) {
    float m = acc[0]; int am = 0;
#pragma unroll
    for (int e = 1; e < NEXP; e++) { if (acc[e] > m) { m = acc[e]; am = e; } }
    float s = 0.f;
#pragma unroll
    for (int e = 0; e < NEXP; e++) s += __expf(acc[e] - m);
    float g = 1.0f / s;   // = exp(m-m)/sum = prob of argmax
    if (mask[t] != 0) {
      int slot = atomicAdd(&counts[am], 1);
      tlist[am * NTOK + slot] = t;
      gate[t] = g;
    }
  }
}

// ---------------- GEMM1: h = relu(X_e @ w1[e]), h bf16 [NTOK][FFN] ----------------
__global__ __launch_bounds__(256) void gemm1_kernel(
    const float* __restrict__ x, const float* __restrict__ w1,
    const int* __restrict__ counts, const int* __restrict__ tlist,
    __bf16* __restrict__ h)
{
  const int NT = FFN / BN; // 64
  int bx = blockIdx.x;
  int nt = bx % NT;
  int mt = (bx / NT) % MT;
  int e  = bx / (NT * MT);
  int cnt = counts[e];
  int m0 = mt * BM;
  if (m0 >= cnt) return;
  int n0 = nt * BN;

  __shared__ __bf16 Asm[BM][LDSTR];
  __shared__ __bf16 Bsm[BN][LDSTR];
  __shared__ int toks[BM];

  int tid = threadIdx.x;
  if (tid < BM) {
    int idx = m0 + tid;
    toks[tid] = (idx < cnt) ? tlist[e * NTOK + idx] : -1;
  }
  __syncthreads();

  int lane = tid & 63;
  int w = tid >> 6;
  int wm = w >> 1, wn = w & 1;
  int r16 = lane & 15;
  int quad = lane >> 4;

  f32x4 acc[2][2] = {};

  const float* w1e = w1 + (size_t)e * DMODEL * FFN;

  for (int k0 = 0; k0 < DMODEL; k0 += BK) {
    // stage A: BM x BK (gather rows via token list), fp32 -> bf16
#pragma unroll
    for (int it = 0; it < 4; it++) {
      int q = it * 256 + tid;
      int r  = q >> 4;
      int c4 = (q & 15) << 2;
      bf16x4 tmp;
      int tok = toks[r];
      if (tok >= 0) {
        const float4 v = *(const float4*)(x + (size_t)tok * DMODEL + k0 + c4);
        tmp[0] = (__bf16)v.x; tmp[1] = (__bf16)v.y;
        tmp[2] = (__bf16)v.z; tmp[3] = (__bf16)v.w;
      } else {
        tmp[0] = (__bf16)0.f; tmp[1] = (__bf16)0.f;
        tmp[2] = (__bf16)0.f; tmp[3] = (__bf16)0.f;
      }
      *(bf16x4*)&Asm[r][c4] = tmp;
    }
    // stage B transposed: Bsm[n][k] <- w1[e][k0+k][n0+n]
#pragma unroll
    for (int it = 0; it < 4; it++) {
      int q = it * 256 + tid;
      int kr = q >> 4;
      int c4 = (q & 15) << 2;
      const float4 v = *(const float4*)(w1e + (size_t)(k0 + kr) * FFN + n0 + c4);
      Bsm[c4 + 0][kr] = (__bf16)v.x;
      Bsm[c4 + 1][kr] = (__bf16)v.y;
      Bsm[c4 + 2][kr] = (__bf16)v.z;
      Bsm[c4 + 3][kr] = (__bf16)v.w;
    }
    __syncthreads();

#pragma unroll
    for (int half = 0; half < 2; half++) {
      int kb = half * 32 + (quad << 3);
      bf16x8 a0 = *(const bf16x8*)&Asm[wm * 32 + r16][kb];
      bf16x8 a1 = *(const bf16x8*)&Asm[wm * 32 + 16 + r16][kb];
      bf16x8 b0 = *(const bf16x8*)&Bsm[wn * 32 + r16][kb];
      bf16x8 b1 = *(const bf16x8*)&Bsm[wn * 32 + 16 + r16][kb];
      acc[0][0] = __builtin_amdgcn_mfma_f32_16x16x32_bf16(a0, b0, acc[0][0], 0, 0, 0);
      acc[0][1] = __builtin_amdgcn_mfma_f32_16x16x32_bf16(a0, b1, acc[0][1], 0, 0, 0);
      acc[1][0] = __builtin_amdgcn_mfma_f32_16x16x32_bf16(a1, b0, acc[1][0], 0, 0, 0);
      acc[1][1] = __builtin_amdgcn_mfma_f32_16x16x32_bf16(a1, b1, acc[1][1], 0, 0, 0);
    }
    __syncthreads();
  }

  // epilogue: relu -> bf16 h
#pragma unroll
  for (int mf = 0; mf < 2; mf++) {
#pragma unroll
    for (int nf = 0; nf < 2; nf++) {
#pragma unroll
      for (int i = 0; i < 4; i++) {
        int row = wm * 32 + mf * 16 + (quad << 2) + i;
        int tok = toks[row];
        if (tok >= 0) {
          int col = n0 + wn * 32 + nf * 16 + r16;
          h[(size_t)tok * FFN + col] = (__bf16)fmaxf(acc[mf][nf][i], 0.f);
        }
      }
    }
  }
}

// ---------------- GEMM2: out = (h_e @ w2[e]) * gate, scatter ----------------
__global__ __launch_bounds__(256) void gemm2_kernel(
    const __bf16* __restrict__ h, const float* __restrict__ w2,
    const int* __restrict__ counts, const int* __restrict__ tlist,
    const float* __restrict__ gate, float* __restrict__ out)
{
  const int NT = DMODEL / BN; // 16
  int bx = blockIdx.x;
  int nt = bx % NT;
  int mt = (bx / NT) % MT;
  int e  = bx / (NT * MT);
  int cnt = counts[e];
  int m0 = mt * BM;
  if (m0 >= cnt) return;
  int n0 = nt * BN;

  __shared__ __bf16 Asm[BM][LDSTR];
  __shared__ __bf16 Bsm[BN][LDSTR];
  __shared__ int toks[BM];

  int tid = threadIdx.x;
  if (tid < BM) {
    int idx = m0 + tid;
    toks[tid] = (idx < cnt) ? tlist[e * NTOK + idx] : -1;
  }
  __syncthreads();

  int lane = tid & 63;
  int w = tid >> 6;
  int wm = w >> 1, wn = w & 1;
  int r16 = lane & 15;
  int quad = lane >> 4;

  f32x4 acc[2][2] = {};

  const float* w2e = w2 + (size_t)e * FFN * DMODEL;

  for (int k0 = 0; k0 < FFN; k0 += BK) {
    // stage A: bf16 h rows (gathered)
#pragma unroll
    for (int it = 0; it < 4; it++) {
      int q = it * 256 + tid;
      int r  = q >> 4;
      int c4 = (q & 15) << 2;
      bf16x4 tmp;
      int tok = toks[r];
      if (tok >= 0) {
        tmp = *(const bf16x4*)(h + (size_t)tok * FFN + k0 + c4);
      } else {
        tmp[0] = (__bf16)0.f; tmp[1] = (__bf16)0.f;
        tmp[2] = (__bf16)0.f; tmp[3] = (__bf16)0.f;
      }
      *(bf16x4*)&Asm[r][c4] = tmp;
    }
    // stage B transposed: Bsm[n][k] <- w2[e][k0+k][n0+n]
#pragma unroll
    for (int it = 0; it < 4; it++) {
      int q = it * 256 + tid;
      int kr = q >> 4;
      int c4 = (q & 15) << 2;
      const float4 v = *(const float4*)(w2e + (size_t)(k0 + kr) * DMODEL + n0 + c4);
      Bsm[c4 + 0][kr] = (__bf16)v.x;
      Bsm[c4 + 1][kr] = (__bf16)v.y;
      Bsm[c4 + 2][kr] = (__bf16)v.z;
      Bsm[c4 + 3][kr] = (__bf16)v.w;
    }
    __syncthreads();

#pragma unroll
    for (int half = 0; half < 2; half++) {
      int kb = half * 32 + (quad << 3);
      bf16x8 a0 = *(const bf16x8*)&Asm[wm * 32 + r16][kb];
      bf16x8 a1 = *(const bf16x8*)&Asm[wm * 32 + 16 + r16][kb];
      bf16x8 b0 = *(const bf16x8*)&Bsm[wn * 32 + r16][kb];
      bf16x8 b1 = *(const bf16x8*)&Bsm[wn * 32 + 16 + r16][kb];
      acc[0][0] = __builtin_amdgcn_mfma_f32_16x16x32_bf16(a0, b0, acc[0][0], 0, 0, 0);
      acc[0][1] = __builtin_amdgcn_mfma_f32_16x16x32_bf16(a0, b1, acc[0][1], 0, 0, 0);
      acc[1][0] = __builtin_amdgcn_mfma_f32_16x16x32_bf16(a1, b0, acc[1][0], 0, 0, 0);
      acc[1][1] = __builtin_amdgcn_mfma_f32_16x16x32_bf16(a1, b1, acc[1][1], 0, 0, 0);
    }
    __syncthreads();
  }

  // epilogue: scale by gate, scatter fp32
#pragma unroll
  for (int mf = 0; mf < 2; mf++) {
#pragma unroll
    for (int nf = 0; nf < 2; nf++) {
#pragma unroll
      for (int i = 0; i < 4; i++) {
        int row = wm * 32 + mf * 16 + (quad << 2) + i;
        int tok = toks[row];
        if (tok >= 0) {
          float g = gate[tok];
          int col = n0 + wn * 32 + nf * 16 + r16;
          out[(size_t)tok * DMODEL + col] = acc[mf][nf][i] * g;
        }
      }
    }
  }
}

extern "C" void kernel_launch(void* const* d_in, const int* in_sizes, int n_in,
                              void* d_out, int out_size, void* d_ws, size_t ws_size,
                              hipStream_t stream) {
  const float* x    = (const float*)d_in[0];
  const int*   mask = (const int*)d_in[1];
  const float* rw   = (const float*)d_in[2];
  const float* w1   = (const float*)d_in[3];
  const float* w2   = (const float*)d_in[4];
  float* out = (float*)d_out;

  char* ws = (char*)d_ws;
  int*    counts = (int*)ws;                                   // 8 ints
  int*    tlist  = (int*)(ws + 1024);                          // 8*2048 ints = 64KB
  float*  gate   = (float*)(ws + 1024 + NEXP * NTOK * 4);      // 2048 floats
  __bf16* h      = (__bf16*)(ws + (1 << 17));                  // 2048*4096 bf16 = 16MB

  hipMemsetAsync(counts, 0, 1024, stream);
  hipMemsetAsync(out, 0, (size_t)out_size * sizeof(float), stream);

  router_kernel<<<NTOK / 4, 256, 0, stream>>>(x, mask, rw, counts, tlist, gate);
  gemm1_kernel<<<NEXP * MT * (FFN / BN), 256, 0, stream>>>(x, w1, counts, tlist, h);
  gemm2_kernel<<<NEXP * MT * (DMODEL / BN), 256, 0, stream>>>(h, w2, counts, tlist, gate, out);
}

// Round 2
// 209.106 us; speedup vs baseline: 1.8422x; 1.8422x over previous
//
#include <hip/hip_runtime.h>
#include <hip/hip_bf16.h>

#define NTOK 2048      // B*T
#define DMODEL 1024
#define NEXP 8
#define FFN 4096
#define MT 32          // max m-tiles per expert (2048/64)
#define BM 64
#define BN 64
#define BK 64
#define LDSTR 88       // fallback-path LDS stride (bf16)
#define PSTR 72        // pre-transposed-path LDS stride (bf16): 144B rows, 16B aligned
#define NSPLIT 4       // gemm2 split-K factor

typedef __bf16 bf16x8 __attribute__((ext_vector_type(8)));
typedef __bf16 bf16x4 __attribute__((ext_vector_type(4)));
typedef float f32x4 __attribute__((ext_vector_type(4)));

// ---------------- router ----------------
__global__ __launch_bounds__(256) void router_kernel(
    const float* __restrict__ x, const int* __restrict__ mask,
    const float* __restrict__ rw, int* __restrict__ counts,
    int* __restrict__ tlist, float* __restrict__ gate)
{
  int wid  = threadIdx.x >> 6;
  int lane = threadIdx.x & 63;
  int t = blockIdx.x * 4 + wid;
  if (t >= NTOK) return;

  float acc[NEXP];
#pragma unroll
  for (int e = 0; e < NEXP; e++) acc[e] = 0.f;

  const float* xr = x + (size_t)t * DMODEL;
  for (int i = 0; i < DMODEL / 64; i++) {
    int d = lane + i * 64;
    float xv = xr[d];
#pragma unroll
    for (int e = 0; e < NEXP; e++) acc[e] += xv * rw[e * DMODEL + d];
  }
#pragma unroll
  for (int e = 0; e < NEXP; e++) {
#pragma unroll
    for (int s = 1; s < 64; s <<= 1) acc[e] += __shfl_xor(acc[e], s, 64);
  }

  if (lane == 0) {
    float m = acc[0]; int am = 0;
#pragma unroll
    for (int e = 1; e < NEXP; e++) { if (acc[e] > m) { m = acc[e]; am = e; } }
    float s = 0.f;
#pragma unroll
    for (int e = 0; e < NEXP; e++) s += __expf(acc[e] - m);
    float g = 1.0f / s;   // prob of argmax
    if (mask[t] != 0) {
      int slot = atomicAdd(&counts[am], 1);
      tlist[am * NTOK + slot] = t;
      gate[t] = g;
    }
  }
}

// ---------------- transpose+convert: in [E][R][C] fp32 -> out [E][C][R] bf16 ----
__global__ __launch_bounds__(256) void transpose_bf16_kernel(
    const float* __restrict__ in, __bf16* __restrict__ outp, int R, int C)
{
  __shared__ float t[64][65];   // pad 65: column reads conflict-light
  int e  = blockIdx.z;
  int c0 = blockIdx.x * 64;
  int r0 = blockIdx.y * 64;
  const float* ine  = in   + (size_t)e * R * C;
  __bf16*      oute = outp + (size_t)e * R * C;
  int tid = threadIdx.x;

#pragma unroll
  for (int it = 0; it < 4; it++) {
    int r  = it * 16 + (tid >> 4);
    int c4 = (tid & 15) << 2;
    const float4 v = *(const float4*)(ine + (size_t)(r0 + r) * C + c0 + c4);
    t[r][c4 + 0] = v.x; t[r][c4 + 1] = v.y;
    t[r][c4 + 2] = v.z; t[r][c4 + 3] = v.w;
  }
  __syncthreads();
#pragma unroll
  for (int it = 0; it < 4; it++) {
    int c  = it * 16 + (tid >> 4);
    int i4 = (tid & 15) << 2;
    bf16x4 o;
#pragma unroll
    for (int j = 0; j < 4; j++) o[j] = (__bf16)t[i4 + j][c];
    *(bf16x4*)(oute + (size_t)(c0 + c) * R + r0 + i4) = o;
  }
}

// ---------------- GEMM1 (pre-transposed): h = relu(X_e @ w1[e]) ----------------
__global__ __launch_bounds__(256) void gemm1_pret(
    const float* __restrict__ x, const __bf16* __restrict__ w1t,
    const int* __restrict__ counts, const int* __restrict__ tlist,
    __bf16* __restrict__ h)
{
  const int NT = FFN / BN; // 64
  int bx = blockIdx.x;
  int nt = bx % NT;
  int mt = (bx / NT) % MT;
  int e  = bx / (NT * MT);
  int cnt = counts[e];
  int m0 = mt * BM;
  if (m0 >= cnt) return;
  int n0 = nt * BN;

  __shared__ __bf16 Asm[BM][PSTR];
  __shared__ __bf16 Bsm[BN][PSTR];
  __shared__ int toks[BM];

  int tid = threadIdx.x;
  if (tid < BM) {
    int idx = m0 + tid;
    toks[tid] = (idx < cnt) ? tlist[e * NTOK + idx] : -1;
  }
  __syncthreads();

  int lane = tid & 63;
  int w = tid >> 6;
  int wm = w >> 1, wn = w & 1;
  int r16 = lane & 15;
  int quad = lane >> 4;

  f32x4 acc[2][2] = {};
  const __bf16* w1e = w1t + (size_t)e * DMODEL * FFN;  // [FFN][DMODEL]

  for (int k0 = 0; k0 < DMODEL; k0 += BK) {
    // A: gather fp32 x rows -> bf16
#pragma unroll
    for (int it = 0; it < 4; it++) {
      int q = it * 256 + tid;
      int r  = q >> 4;
      int c4 = (q & 15) << 2;
      bf16x4 tmp;
      int tok = toks[r];
      if (tok >= 0) {
        const float4 v = *(const float4*)(x + (size_t)tok * DMODEL + k0 + c4);
        tmp[0] = (__bf16)v.x; tmp[1] = (__bf16)v.y;
        tmp[2] = (__bf16)v.z; tmp[3] = (__bf16)v.w;
      } else {
        tmp[0] = (__bf16)0.f; tmp[1] = (__bf16)0.f;
        tmp[2] = (__bf16)0.f; tmp[3] = (__bf16)0.f;
      }
      *(bf16x4*)&Asm[r][c4] = tmp;
    }
    // B: linear bf16x8 copy of w1t rows (k-contiguous)
#pragma unroll
    for (int it = 0; it < 2; it++) {
      int chunk = it * 256 + tid;
      int row = chunk >> 3;
      int c8  = (chunk & 7) << 3;
      *(bf16x8*)&Bsm[row][c8] =
          *(const bf16x8*)(w1e + (size_t)(n0 + row) * DMODEL + k0 + c8);
    }
    __syncthreads();

#pragma unroll
    for (int half = 0; half < 2; half++) {
      int kb = half * 32 + (quad << 3);
      bf16x8 a0 = *(const bf16x8*)&Asm[wm * 32 + r16][kb];
      bf16x8 a1 = *(const bf16x8*)&Asm[wm * 32 + 16 + r16][kb];
      bf16x8 b0 = *(const bf16x8*)&Bsm[wn * 32 + r16][kb];
      bf16x8 b1 = *(const bf16x8*)&Bsm[wn * 32 + 16 + r16][kb];
      acc[0][0] = __builtin_amdgcn_mfma_f32_16x16x32_bf16(a0, b0, acc[0][0], 0, 0, 0);
      acc[0][1] = __builtin_amdgcn_mfma_f32_16x16x32_bf16(a0, b1, acc[0][1], 0, 0, 0);
      acc[1][0] = __builtin_amdgcn_mfma_f32_16x16x32_bf16(a1, b0, acc[1][0], 0, 0, 0);
      acc[1][1] = __builtin_amdgcn_mfma_f32_16x16x32_bf16(a1, b1, acc[1][1], 0, 0, 0);
    }
    __syncthreads();
  }

#pragma unroll
  for (int mf = 0; mf < 2; mf++) {
#pragma unroll
    for (int nf = 0; nf < 2; nf++) {
#pragma unroll
      for (int i = 0; i < 4; i++) {
        int row = wm * 32 + mf * 16 + (quad << 2) + i;
        int tok = toks[row];
        if (tok >= 0) {
          int col = n0 + wn * 32 + nf * 16 + r16;
          h[(size_t)tok * FFN + col] = (__bf16)fmaxf(acc[mf][nf][i], 0.f);
        }
      }
    }
  }
}

// ------- GEMM2 (pre-transposed, split-K): out += (h_e @ w2[e]) * gate ----------
__global__ __launch_bounds__(256) void gemm2_pret(
    const __bf16* __restrict__ h, const __bf16* __restrict__ w2t,
    const int* __restrict__ counts, const int* __restrict__ tlist,
    const float* __restrict__ gate, float* __restrict__ out)
{
  const int NT = DMODEL / BN; // 16
  int bx = blockIdx.x;
  int nt = bx % NT;
  int mt = (bx / NT) % MT;
  int e  = (bx / (NT * MT)) % NEXP;
  int sp = bx / (NT * MT * NEXP);
  int cnt = counts[e];
  int m0 = mt * BM;
  if (m0 >= cnt) return;
  int n0 = nt * BN;

  __shared__ __bf16 Asm[BM][PSTR];
  __shared__ __bf16 Bsm[BN][PSTR];
  __shared__ int toks[BM];

  int tid = threadIdx.x;
  if (tid < BM) {
    int idx = m0 + tid;
    toks[tid] = (idx < cnt) ? tlist[e * NTOK + idx] : -1;
  }
  __syncthreads();

  int lane = tid & 63;
  int w = tid >> 6;
  int wm = w >> 1, wn = w & 1;
  int r16 = lane & 15;
  int quad = lane >> 4;

  f32x4 acc[2][2] = {};
  const __bf16* w2e = w2t + (size_t)e * FFN * DMODEL;  // [DMODEL][FFN]

  const int KS = FFN / NSPLIT;   // 1024
  for (int k0 = sp * KS; k0 < (sp + 1) * KS; k0 += BK) {
    // A: gather h rows (bf16, k-contiguous)
#pragma unroll
    for (int it = 0; it < 2; it++) {
      int chunk = it * 256 + tid;
      int row = chunk >> 3;
      int c8  = (chunk & 7) << 3;
      int tok = toks[row];
      bf16x8 tmp;
      if (tok >= 0) {
        tmp = *(const bf16x8*)(h + (size_t)tok * FFN + k0 + c8);
      } else {
#pragma unroll
        for (int j = 0; j < 8; j++) tmp[j] = (__bf16)0.f;
      }
      *(bf16x8*)&Asm[row][c8] = tmp;
    }
    // B: linear bf16x8 copy of w2t rows (k-contiguous)
#pragma unroll
    for (int it = 0; it < 2; it++) {
      int chunk = it * 256 + tid;
      int row = chunk >> 3;
      int c8  = (chunk & 7) << 3;
      *(bf16x8*)&Bsm[row][c8] =
          *(const bf16x8*)(w2e + (size_t)(n0 + row) * FFN + k0 + c8);
    }
    __syncthreads();

#pragma unroll
    for (int half = 0; half < 2; half++) {
      int kb = half * 32 + (quad << 3);
      bf16x8 a0 = *(const bf16x8*)&Asm[wm * 32 + r16][kb];
      bf16x8 a1 = *(const bf16x8*)&Asm[wm * 32 + 16 + r16][kb];
      bf16x8 b0 = *(const bf16x8*)&Bsm[wn * 32 + r16][kb];
      bf16x8 b1 = *(const bf16x8*)&Bsm[wn * 32 + 16 + r16][kb];
      acc[0][0] = __builtin_amdgcn_mfma_f32_16x16x32_bf16(a0, b0, acc[0][0], 0, 0, 0);
      acc[0][1] = __builtin_amdgcn_mfma_f32_16x16x32_bf16(a0, b1, acc[0][1], 0, 0, 0);
      acc[1][0] = __builtin_amdgcn_mfma_f32_16x16x32_bf16(a1, b0, acc[1][0], 0, 0, 0);
      acc[1][1] = __builtin_amdgcn_mfma_f32_16x16x32_bf16(a1, b1, acc[1][1], 0, 0, 0);
    }
    __syncthreads();
  }

#pragma unroll
  for (int mf = 0; mf < 2; mf++) {
#pragma unroll
    for (int nf = 0; nf < 2; nf++) {
#pragma unroll
      for (int i = 0; i < 4; i++) {
        int row = wm * 32 + mf * 16 + (quad << 2) + i;
        int tok = toks[row];
        if (tok >= 0) {
          float g = gate[tok];
          int col = n0 + wn * 32 + nf * 16 + r16;
          __hip_atomic_fetch_add(&out[(size_t)tok * DMODEL + col],
                                 acc[mf][nf][i] * g,
                                 __ATOMIC_RELAXED, __HIP_MEMORY_SCOPE_AGENT);
        }
      }
    }
  }
}

// ---------------- fallback kernels (small ws): original path ----------------
__global__ __launch_bounds__(256) void gemm1_kernel(
    const float* __restrict__ x, const float* __restrict__ w1,
    const int* __restrict__ counts, const int* __restrict__ tlist,
    __bf16* __restrict__ h)
{
  const int NT = FFN / BN;
  int bx = blockIdx.x;
  int nt = bx % NT;
  int mt = (bx / NT) % MT;
  int e  = bx / (NT * MT);
  int cnt = counts[e];
  int m0 = mt * BM;
  if (m0 >= cnt) return;
  int n0 = nt * BN;

  __shared__ __bf16 Asm[BM][LDSTR];
  __shared__ __bf16 Bsm[BN][LDSTR];
  __shared__ int toks[BM];

  int tid = threadIdx.x;
  if (tid < BM) {
    int idx = m0 + tid;
    toks[tid] = (idx < cnt) ? tlist[e * NTOK + idx] : -1;
  }
  __syncthreads();

  int lane = tid & 63;
  int w = tid >> 6;
  int wm = w >> 1, wn = w & 1;
  int r16 = lane & 15;
  int quad = lane >> 4;

  f32x4 acc[2][2] = {};
  const float* w1e = w1 + (size_t)e * DMODEL * FFN;

  for (int k0 = 0; k0 < DMODEL; k0 += BK) {
#pragma unroll
    for (int it = 0; it < 4; it++) {
      int q = it * 256 + tid;
      int r  = q >> 4;
      int c4 = (q & 15) << 2;
      bf16x4 tmp;
      int tok = toks[r];
      if (tok >= 0) {
        const float4 v = *(const float4*)(x + (size_t)tok * DMODEL + k0 + c4);
        tmp[0] = (__bf16)v.x; tmp[1] = (__bf16)v.y;
        tmp[2] = (__bf16)v.z; tmp[3] = (__bf16)v.w;
      } else {
        tmp[0] = (__bf16)0.f; tmp[1] = (__bf16)0.f;
        tmp[2] = (__bf16)0.f; tmp[3] = (__bf16)0.f;
      }
      *(bf16x4*)&Asm[r][c4] = tmp;
    }
#pragma unroll
    for (int it = 0; it < 4; it++) {
      int q = it * 256 + tid;
      int kr = q >> 4;
      int c4 = (q & 15) << 2;
      const float4 v = *(const float4*)(w1e + (size_t)(k0 + kr) * FFN + n0 + c4);
      Bsm[c4 + 0][kr] = (__bf16)v.x;
      Bsm[c4 + 1][kr] = (__bf16)v.y;
      Bsm[c4 + 2][kr] = (__bf16)v.z;
      Bsm[c4 + 3][kr] = (__bf16)v.w;
    }
    __syncthreads();

#pragma unroll
    for (int half = 0; half < 2; half++) {
      int kb = half * 32 + (quad << 3);
      bf16x8 a0 = *(const bf16x8*)&Asm[wm * 32 + r16][kb];
      bf16x8 a1 = *(const bf16x8*)&Asm[wm * 32 + 16 + r16][kb];
      bf16x8 b0 = *(const bf16x8*)&Bsm[wn * 32 + r16][kb];
      bf16x8 b1 = *(const bf16x8*)&Bsm[wn * 32 + 16 + r16][kb];
      acc[0][0] = __builtin_amdgcn_mfma_f32_16x16x32_bf16(a0, b0, acc[0][0], 0, 0, 0);
      acc[0][1] = __builtin_amdgcn_mfma_f32_16x16x32_bf16(a0, b1, acc[0][1], 0, 0, 0);
      acc[1][0] = __builtin_amdgcn_mfma_f32_16x16x32_bf16(a1, b0, acc[1][0], 0, 0, 0);
      acc[1][1] = __builtin_amdgcn_mfma_f32_16x16x32_bf16(a1, b1, acc[1][1], 0, 0, 0);
    }
    __syncthreads();
  }

#pragma unroll
  for (int mf = 0; mf < 2; mf++) {
#pragma unroll
    for (int nf = 0; nf < 2; nf++) {
#pragma unroll
      for (int i = 0; i < 4; i++) {
        int row = wm * 32 + mf * 16 + (quad << 2) + i;
        int tok = toks[row];
        if (tok >= 0) {
          int col = n0 + wn * 32 + nf * 16 + r16;
          h[(size_t)tok * FFN + col] = (__bf16)fmaxf(acc[mf][nf][i], 0.f);
        }
      }
    }
  }
}

__global__ __launch_bounds__(256) void gemm2_kernel(
    const __bf16* __restrict__ h, const float* __restrict__ w2,
    const int* __restrict__ counts, const int* __restrict__ tlist,
    const float* __restrict__ gate, float* __restrict__ out)
{
  const int NT = DMODEL / BN;
  int bx = blockIdx.x;
  int nt = bx % NT;
  int mt = (bx / NT) % MT;
  int e  = bx / (NT * MT);
  int cnt = counts[e];
  int m0 = mt * BM;
  if (m0 >= cnt) return;
  int n0 = nt * BN;

  __shared__ __bf16 Asm[BM][LDSTR];
  __shared__ __bf16 Bsm[BN][LDSTR];
  __shared__ int toks[BM];

  int tid = threadIdx.x;
  if (tid < BM) {
    int idx = m0 + tid;
    toks[tid] = (idx < cnt) ? tlist[e * NTOK + idx] : -1;
  }
  __syncthreads();

  int lane = tid & 63;
  int w = tid >> 6;
  int wm = w >> 1, wn = w & 1;
  int r16 = lane & 15;
  int quad = lane >> 4;

  f32x4 acc[2][2] = {};
  const float* w2e = w2 + (size_t)e * FFN * DMODEL;

  for (int k0 = 0; k0 < FFN; k0 += BK) {
#pragma unroll
    for (int it = 0; it < 4; it++) {
      int q = it * 256 + tid;
      int r  = q >> 4;
      int c4 = (q & 15) << 2;
      bf16x4 tmp;
      int tok = toks[r];
      if (tok >= 0) {
        tmp = *(const bf16x4*)(h + (size_t)tok * FFN + k0 + c4);
      } else {
        tmp[0] = (__bf16)0.f; tmp[1] = (__bf16)0.f;
        tmp[2] = (__bf16)0.f; tmp[3] = (__bf16)0.f;
      }
      *(bf16x4*)&Asm[r][c4] = tmp;
    }
#pragma unroll
    for (int it = 0; it < 4; it++) {
      int q = it * 256 + tid;
      int kr = q >> 4;
      int c4 = (q & 15) << 2;
      const float4 v = *(const float4*)(w2e + (size_t)(k0 + kr) * DMODEL + n0 + c4);
      Bsm[c4 + 0][kr] = (__bf16)v.x;
      Bsm[c4 + 1][kr] = (__bf16)v.y;
      Bsm[c4 + 2][kr] = (__bf16)v.z;
      Bsm[c4 + 3][kr] = (__bf16)v.w;
    }
    __syncthreads();

#pragma unroll
    for (int half = 0; half < 2; half++) {
      int kb = half * 32 + (quad << 3);
      bf16x8 a0 = *(const bf16x8*)&Asm[wm * 32 + r16][kb];
      bf16x8 a1 = *(const bf16x8*)&Asm[wm * 32 + 16 + r16][kb];
      bf16x8 b0 = *(const bf16x8*)&Bsm[wn * 32 + r16][kb];
      bf16x8 b1 = *(const bf16x8*)&Bsm[wn * 32 + 16 + r16][kb];
      acc[0][0] = __builtin_amdgcn_mfma_f32_16x16x32_bf16(a0, b0, acc[0][0], 0, 0, 0);
      acc[0][1] = __builtin_amdgcn_mfma_f32_16x16x32_bf16(a0, b1, acc[0][1], 0, 0, 0);
      acc[1][0] = __builtin_amdgcn_mfma_f32_16x16x32_bf16(a1, b0, acc[1][0], 0, 0, 0);
      acc[1][1] = __builtin_amdgcn_mfma_f32_16x16x32_bf16(a1, b1, acc[1][1], 0, 0, 0);
    }
    __syncthreads();
  }

#pragma unroll
  for (int mf = 0; mf < 2; mf++) {
#pragma unroll
    for (int nf = 0; nf < 2; nf++) {
#pragma unroll
      for (int i = 0; i < 4; i++) {
        int row = wm * 32 + mf * 16 + (quad << 2) + i;
        int tok = toks[row];
        if (tok >= 0) {
          float g = gate[tok];
          int col = n0 + wn * 32 + nf * 16 + r16;
          out[(size_t)tok * DMODEL + col] = acc[mf][nf][i] * g;
        }
      }
    }
  }
}

extern "C" void kernel_launch(void* const* d_in, const int* in_sizes, int n_in,
                              void* d_out, int out_size, void* d_ws, size_t ws_size,
                              hipStream_t stream) {
  const float* x    = (const float*)d_in[0];
  const int*   mask = (const int*)d_in[1];
  const float* rw   = (const float*)d_in[2];
  const float* w1   = (const float*)d_in[3];
  const float* w2   = (const float*)d_in[4];
  float* out = (float*)d_out;

  char* ws = (char*)d_ws;
  int*    counts = (int*)ws;                                   // 1 KB
  int*    tlist  = (int*)(ws + 1024);                          // 64 KB
  float*  gate   = (float*)(ws + 1024 + NEXP * NTOK * 4);      // 8 KB
  __bf16* h      = (__bf16*)(ws + (1 << 17));                  // 16 MB
  size_t  hbytes = (size_t)NTOK * FFN * 2;
  size_t  wbytes = (size_t)NEXP * DMODEL * FFN * 2;            // 64 MB each
  __bf16* w1t    = (__bf16*)(ws + (1 << 17) + hbytes);
  __bf16* w2t    = (__bf16*)(ws + (1 << 17) + hbytes + wbytes);
  size_t  need_full = (size_t)(1 << 17) + hbytes + 2 * wbytes; // ~144 MB

  hipMemsetAsync(counts, 0, 1024, stream);
  hipMemsetAsync(out, 0, (size_t)out_size * sizeof(float), stream);

  router_kernel<<<NTOK / 4, 256, 0, stream>>>(x, mask, rw, counts, tlist, gate);

  if (ws_size >= need_full) {
    // w1 [E][D][F] -> w1t [E][F][D]
    transpose_bf16_kernel<<<dim3(FFN / 64, DMODEL / 64, NEXP), 256, 0, stream>>>(
        w1, w1t, DMODEL, FFN);
    // w2 [E][F][D] -> w2t [E][D][F]
    transpose_bf16_kernel<<<dim3(DMODEL / 64, FFN / 64, NEXP), 256, 0, stream>>>(
        w2, w2t, FFN, DMODEL);
    gemm1_pret<<<NEXP * MT * (FFN / BN), 256, 0, stream>>>(x, w1t, counts, tlist, h);
    gemm2_pret<<<NEXP * MT * (DMODEL / BN) * NSPLIT, 256, 0, stream>>>(
        h, w2t, counts, tlist, gate, out);
  } else {
    gemm1_kernel<<<NEXP * MT * (FFN / BN), 256, 0, stream>>>(x, w1, counts, tlist, h);
    gemm2_kernel<<<NEXP * MT * (DMODEL / BN), 256, 0, stream>>>(h, w2, counts, tlist, gate, out);
  }
}